// Round 3
// baseline (33.232 us; speedup 1.0000x reference)
//
#include <hip/hip_runtime.h>

// QuantumTTEmbedding: TT-factorized embedding lookup.
// id -> (i,j,k) = (id/1600, (id/40)%40, id%40), ij = id/40 = i*40+j.
// Per half (real/imag):
//   out[d][f][e] = sum_{r,s} c1[0][i][d][r] * c2[r][j][f][s] * c3[s][k][e][0]
// Strategy: precompute P[ij][half][(d*4+f)]][s] = sum_r g1*g2  (800x128 f32 =
// 400 KB in d_ws, L2-resident), then gather kernel does 1 global b128 (P row)
// + 4 LDS b128 (g3, 10 KB) + 16 FMA + 1 b128 store per token.

#define V1 20
#define V2 40
#define V3 40
#define D1 4
#define D2 4
#define D3 8
#define RNK 4

#define NIJ (V1*V2)              // 800
#define PROW 128                 // floats per ij row: 2 halves x 64
#define P_BYTES (NIJ*PROW*4)     // 409600 bytes

// ---------------- precompute: P[ij*128 + h*64 + (d*4+f)*4 + s] ----------------
__global__ __launch_bounds__(256) void tt_precompute_kernel(
    const float* __restrict__ cr1, const float* __restrict__ cr2,
    const float* __restrict__ ci1, const float* __restrict__ ci2,
    float* __restrict__ P)
{
    const int tid = blockIdx.x * 256 + threadIdx.x;   // 0 .. 102399
    if (tid >= NIJ * PROW) return;
    const int x  = tid & 63;          // (d*4+f)*4 + s
    const int h  = (tid >> 6) & 1;
    const int ij = tid >> 7;
    const int d = x >> 4, f = (x >> 2) & 3, s = x & 3;
    const int i = ij / V2, j = ij - i * V2;
    const float* c1 = h ? ci1 : cr1;
    const float* c2 = h ? ci2 : cr2;
    float acc = 0.f;
    #pragma unroll
    for (int r = 0; r < RNK; ++r)
        acc += c1[(i*D1 + d)*RNK + r] * c2[((r*V2 + j)*D2 + f)*RNK + s];
    P[tid] = acc;
}

// ---------------- gather: out[t][h*128 + d*32 + f*8 + e] ----------------
#define G3_HALF (RNK*V3*D3)        // 1280 floats
#define G3_IOFF (G3_HALF + 16)     // 1296: imag offset == 16 mod 32 -> bank-disjoint
#define G3_LDS  (G3_IOFF + G3_HALF)

#define TPW 16
#define BLOCK 512

__global__ __launch_bounds__(BLOCK, 8) void tt_gather_kernel(
    const int* __restrict__ ids, const float* __restrict__ P,
    const float* __restrict__ cr3, const float* __restrict__ ci3,
    float* __restrict__ out, int N)
{
    __shared__ __align__(16) float g3[G3_LDS];
    {
        float4* l4 = (float4*)g3;
        const float4* s3r = (const float4*)cr3;
        const float4* s3i = (const float4*)ci3;
        for (int idx = threadIdx.x; idx < G3_HALF/4; idx += BLOCK) {
            l4[idx]             = s3r[idx];
            l4[G3_IOFF/4 + idx] = s3i[idx];
        }
    }
    __syncthreads();

    // lane = h*32 + q, q = (d*4+f)*2 + (e0/4): lane owns out[.. d*32+f*8+e0..e0+3]
    const int lane = threadIdx.x & 63;
    const int h    = lane >> 5;
    const int q    = lane & 31;
    const int e0   = (q & 1) * 4;

    const float* Plane = P + h*64 + (q >> 1)*4;    // + ij*PROW -> float4 of temp[d][f][0..3]
    const float* B3    = g3 + h*G3_IOFF + e0;      // + s*320 + k*8 -> g3[s][e0..e0+3]

    const int wid = blockIdx.x * (BLOCK/64) + (threadIdx.x >> 6);
    const int t0  = wid * TPW;
    if (t0 >= N) return;
    const int nv = (N - t0 < TPW) ? (N - t0) : TPW;

    int packed = 0;
    if (lane < nv) {
        const int id = ids[t0 + lane];
        const int k  = id % V3;
        const int ij = id / V3;                     // = i*V2 + j
        packed = ij | ((k * D3) << 10);
    }

    float* outp = out + (size_t)t0 * 256 + lane * 4;

    #pragma unroll 1
    for (int it = 0; it < nv; ++it) {
        const int p  = __builtin_amdgcn_readlane(packed, it);  // SGPR broadcast
        const int ij = p & 0x3ff;
        const int k8 = p >> 10;

        const float4 Pr = *reinterpret_cast<const float4*>(Plane + ij * PROW);

        const float* b  = B3 + k8;
        const float4 b0 = *reinterpret_cast<const float4*>(b);
        const float4 b1 = *reinterpret_cast<const float4*>(b +     V3*D3);
        const float4 b2 = *reinterpret_cast<const float4*>(b + 2 * V3*D3);
        const float4 b3 = *reinterpret_cast<const float4*>(b + 3 * V3*D3);

        float4 o;
        o.x = Pr.x*b0.x + Pr.y*b1.x + Pr.z*b2.x + Pr.w*b3.x;
        o.y = Pr.x*b0.y + Pr.y*b1.y + Pr.z*b2.y + Pr.w*b3.y;
        o.z = Pr.x*b0.z + Pr.y*b1.z + Pr.z*b2.z + Pr.w*b3.z;
        o.w = Pr.x*b0.w + Pr.y*b1.w + Pr.z*b2.w + Pr.w*b3.w;

        *reinterpret_cast<float4*>(outp) = o;
        outp += 256;
    }
}

// ---------------- fallback (R2 direct kernel) if ws too small ----------------
#define C1_SZ (V1*D1*RNK)
#define C2_SZ (RNK*V2*D2*RNK)
#define C3_SZ (RNK*V3*D3)
#define HALF_SZ (C1_SZ + C2_SZ + C3_SZ)
#define IMAG_OFF (HALF_SZ + 16)
#define LDS_FLOATS (IMAG_OFF + HALF_SZ)

__global__ __launch_bounds__(BLOCK, 8) void tt_embed_direct_kernel(
    const int* __restrict__ ids,
    const float* __restrict__ cr1, const float* __restrict__ cr2, const float* __restrict__ cr3,
    const float* __restrict__ ci1, const float* __restrict__ ci2, const float* __restrict__ ci3,
    float* __restrict__ out, int N)
{
    __shared__ __align__(16) float lds[LDS_FLOATS];
    {
        float4*       l4r = (float4*)lds;
        float4*       l4i = (float4*)(lds + IMAG_OFF);
        const float4* s1r = (const float4*)cr1; const float4* s1i = (const float4*)ci1;
        const float4* s2r = (const float4*)cr2; const float4* s2i = (const float4*)ci2;
        const float4* s3r = (const float4*)cr3; const float4* s3i = (const float4*)ci3;
        for (int idx = threadIdx.x; idx < C1_SZ/4; idx += BLOCK) { l4r[idx] = s1r[idx]; l4i[idx] = s1i[idx]; }
        for (int idx = threadIdx.x; idx < C2_SZ/4; idx += BLOCK) { l4r[C1_SZ/4+idx] = s2r[idx]; l4i[C1_SZ/4+idx] = s2i[idx]; }
        for (int idx = threadIdx.x; idx < C3_SZ/4; idx += BLOCK) { l4r[(C1_SZ+C2_SZ)/4+idx] = s3r[idx]; l4i[(C1_SZ+C2_SZ)/4+idx] = s3i[idx]; }
    }
    __syncthreads();

    const int lane = threadIdx.x & 63;
    const int half = lane >> 5;
    const int q    = lane & 31;
    const int d    = q >> 3;
    const int f    = (q >> 1) & 3;
    const int e0   = (q & 1) * 4;

    const float* base = lds + half * IMAG_OFF;
    const float* B1 = base + d * RNK;
    const float* B2 = base + C1_SZ + f * RNK;
    const float* B3 = base + C1_SZ + C2_SZ + e0;

    const int wid = blockIdx.x * (BLOCK / 64) + (threadIdx.x >> 6);
    const int t0  = wid * TPW;
    if (t0 >= N) return;
    const int nv = (N - t0 < TPW) ? (N - t0) : TPW;

    int packed = 0;
    if (lane < nv) {
        const int id = ids[t0 + lane];
        const int k  = id % V3;
        const int ij = id / V3;
        const int j  = ij % V2;
        const int i  = ij / V2;
        packed = (i * (D1*RNK)) | ((j * (D2*RNK)) << 9) | ((k * D3) << 19);
    }

    float* outp = out + (size_t)t0 * 256 + lane * 4;

    #pragma unroll 1
    for (int it = 0; it < nv; ++it) {
        const int p  = __builtin_amdgcn_readlane(packed, it);
        const int io = p & 0x1ff;
        const int jo = (p >> 9) & 0x3ff;
        const int ko = (p >> 19);

        const float4 g1 = *reinterpret_cast<const float4*>(B1 + io);
        const float* p2 = B2 + jo;
        const float4 a0 = *reinterpret_cast<const float4*>(p2);
        const float4 a1 = *reinterpret_cast<const float4*>(p2 +     V2*D2*RNK);
        const float4 a2 = *reinterpret_cast<const float4*>(p2 + 2 * V2*D2*RNK);
        const float4 a3 = *reinterpret_cast<const float4*>(p2 + 3 * V2*D2*RNK);
        const float tmp0 = g1.x*a0.x + g1.y*a1.x + g1.z*a2.x + g1.w*a3.x;
        const float tmp1 = g1.x*a0.y + g1.y*a1.y + g1.z*a2.y + g1.w*a3.y;
        const float tmp2 = g1.x*a0.z + g1.y*a1.z + g1.z*a2.z + g1.w*a3.z;
        const float tmp3 = g1.x*a0.w + g1.y*a1.w + g1.z*a2.w + g1.w*a3.w;

        const float* p3 = B3 + ko;
        const float4 b0 = *reinterpret_cast<const float4*>(p3);
        const float4 b1 = *reinterpret_cast<const float4*>(p3 +     V3*D3);
        const float4 b2 = *reinterpret_cast<const float4*>(p3 + 2 * V3*D3);
        const float4 b3 = *reinterpret_cast<const float4*>(p3 + 3 * V3*D3);
        float4 o;
        o.x = tmp0*b0.x + tmp1*b1.x + tmp2*b2.x + tmp3*b3.x;
        o.y = tmp0*b0.y + tmp1*b1.y + tmp2*b2.y + tmp3*b3.y;
        o.z = tmp0*b0.z + tmp1*b1.z + tmp2*b2.z + tmp3*b3.z;
        o.w = tmp0*b0.w + tmp1*b1.w + tmp2*b2.w + tmp3*b3.w;

        *reinterpret_cast<float4*>(outp) = o;
        outp += 256;
    }
}

extern "C" void kernel_launch(void* const* d_in, const int* in_sizes, int n_in,
                              void* d_out, int out_size, void* d_ws, size_t ws_size,
                              hipStream_t stream) {
    const int*   ids = (const int*)d_in[0];
    const float* cr1 = (const float*)d_in[1];
    const float* cr2 = (const float*)d_in[2];
    const float* cr3 = (const float*)d_in[3];
    const float* ci1 = (const float*)d_in[4];
    const float* ci2 = (const float*)d_in[5];
    const float* ci3 = (const float*)d_in[6];
    float* out = (float*)d_out;

    const int N = in_sizes[0];
    const int tokens_per_block = (BLOCK / 64) * TPW;                   // 128
    const int blocks = (N + tokens_per_block - 1) / tokens_per_block;  // 1024 @ N=131072

    if (ws_size >= (size_t)P_BYTES) {
        float* P = (float*)d_ws;
        tt_precompute_kernel<<<(NIJ*PROW + 255)/256, 256, 0, stream>>>(cr1, cr2, ci1, ci2, P);
        tt_gather_kernel<<<blocks, BLOCK, 0, stream>>>(ids, P, cr3, ci3, out, N);
    } else {
        tt_embed_direct_kernel<<<blocks, BLOCK, 0, stream>>>(ids, cr1, cr2, cr3, ci1, ci2, ci3, out, N);
    }
}

// Round 4
// 32.329 us; speedup vs baseline: 1.0279x; 1.0279x over previous
//
#include <hip/hip_runtime.h>

// QuantumTTEmbedding: TT-factorized embedding lookup.
// id -> (i,j,k) = (id/1600, (id/40)%40, id%40).
// Per half h (real/imag):
//   out[d][f][e] = sum_{r,s} c1[0][i][d][r] * c2[r][j][f][s] * c3[s][k][e][0]
// Output [N][256] f32, flat (h*128 + d*32 + f*8 + e).
//
// Mapping: 2 tokens per wave per iteration.
//   lane = p*32 + q,  p = token parity, q = h*16 + d*4 + f
//   each lane computes all 8 e-outputs of its (h,d,f) for its token.
// LDS traffic: 13 ds_read_b128 per token PAIR (6.5/token, 78 cyc/token)
//   vs 9/token (108 cyc) in the 1-token mapping -> below the HBM-write
//   floor of ~96 cyc/token. Write-bound by design.

#define V1 20
#define V2 40
#define V3 40
#define D1 4
#define D2 4
#define D3 8
#define RNK 4

#define C1_SZ (V1*D1*RNK)          // 320 floats
#define C2_SZ (RNK*V2*D2*RNK)      // 2560 floats
#define C3_SZ (RNK*V3*D3)          // 1280 floats
#define HALF_SZ (C1_SZ + C2_SZ + C3_SZ)   // 4160
#define IMAG_OFF (HALF_SZ + 16)    // 4176: imag base == 16 mod 32 banks -> complementary
#define LDS_FLOATS (IMAG_OFF + HALF_SZ)   // 8336 floats = 33.4 KB

#define TPW 16                     // tokens per wave (8 pair-iterations)
#define BLOCK 512                  // 8 waves/block

__global__ __launch_bounds__(BLOCK, 8) void tt_embed_kernel(
    const int* __restrict__ ids,
    const float* __restrict__ cr1, const float* __restrict__ cr2, const float* __restrict__ cr3,
    const float* __restrict__ ci1, const float* __restrict__ ci2, const float* __restrict__ ci3,
    float* __restrict__ out, int N)
{
    __shared__ __align__(16) float lds[LDS_FLOATS];

    // ---- stage cores into LDS, float4-vectorized ----
    {
        float4*       l4r = (float4*)lds;
        float4*       l4i = (float4*)(lds + IMAG_OFF);
        const float4* s1r = (const float4*)cr1; const float4* s1i = (const float4*)ci1;
        const float4* s2r = (const float4*)cr2; const float4* s2i = (const float4*)ci2;
        const float4* s3r = (const float4*)cr3; const float4* s3i = (const float4*)ci3;
        for (int idx = threadIdx.x; idx < C1_SZ/4; idx += BLOCK) {
            l4r[idx] = s1r[idx]; l4i[idx] = s1i[idx];
        }
        for (int idx = threadIdx.x; idx < C2_SZ/4; idx += BLOCK) {
            l4r[C1_SZ/4 + idx] = s2r[idx]; l4i[C1_SZ/4 + idx] = s2i[idx];
        }
        for (int idx = threadIdx.x; idx < C3_SZ/4; idx += BLOCK) {
            l4r[(C1_SZ+C2_SZ)/4 + idx] = s3r[idx]; l4i[(C1_SZ+C2_SZ)/4 + idx] = s3i[idx];
        }
    }
    __syncthreads();

    // ---- lane roles ----
    const int lane = threadIdx.x & 63;
    const int p    = lane >> 5;          // token parity within pair
    const int q    = lane & 31;
    const int h    = q >> 4;             // 0 = real, 1 = imag
    const int df   = q & 15;             // d*4 + f
    const int d    = df >> 2;
    const int f    = df & 3;

    const float* baseh = lds + h * IMAG_OFF;
    const float* G1 = baseh + d * RNK;                 // + i*16        -> c1[i][d][0..3]
    const float* G2 = baseh + C1_SZ + f * RNK;         // + j*16 (+r*640 imm) -> c2[r][j][f][0..3]
    const float* G3 = baseh + C1_SZ + C2_SZ;           // + k*8 (+s*320 imm)  -> c3[s][k][0..7]

    const int wid = blockIdx.x * (BLOCK / 64) + (threadIdx.x >> 6);
    const int t0  = wid * TPW;
    if (t0 >= N) return;

    // ---- preload this wave's 16 token ids; pack LDS float-offsets ----
    int packed = 0;
    if (lane < TPW && (t0 + lane) < N) {
        const int id = ids[t0 + lane];
        const int k  = id % V3;
        const int ij = id / V3;
        const int j  = ij % V2;
        const int i  = ij / V2;
        // i*16 (9b) | j*16 << 9 (10b) | k*8 << 19 (9b)
        packed = (i * (D1*RNK)) | ((j * (D2*RNK)) << 9) | ((k * D3) << 19);
    }

    // lane's output slice: token (t0 + 2*it + p), floats [h*128 + df*8 .. +7]
    float* outp = out + (size_t)(t0 + p) * 256 + h * 128 + df * 8;

    #pragma unroll 1
    for (int it = 0; it < TPW/2; ++it) {
        const int tt = t0 + 2*it;
        const int pa = __builtin_amdgcn_readlane(packed, 2*it);
        const int pb = __builtin_amdgcn_readlane(packed, 2*it + 1);
        const int pk = p ? pb : pa;

        const int io = pk & 0x1ff;
        const int jo = (pk >> 9) & 0x3ff;
        const int ko = pk >> 19;

        // phase 1: temp[s] = sum_r c1[i][d][r] * c2[r][j][f][s]
        const float4 g1 = *reinterpret_cast<const float4*>(G1 + io);
        const float* p2 = G2 + jo;
        const float4 a0 = *reinterpret_cast<const float4*>(p2);
        const float4 a1 = *reinterpret_cast<const float4*>(p2 +     V2*D2*RNK);
        const float4 a2 = *reinterpret_cast<const float4*>(p2 + 2 * V2*D2*RNK);
        const float4 a3 = *reinterpret_cast<const float4*>(p2 + 3 * V2*D2*RNK);
        const float tmp0 = g1.x*a0.x + g1.y*a1.x + g1.z*a2.x + g1.w*a3.x;
        const float tmp1 = g1.x*a0.y + g1.y*a1.y + g1.z*a2.y + g1.w*a3.y;
        const float tmp2 = g1.x*a0.z + g1.y*a1.z + g1.z*a2.z + g1.w*a3.z;
        const float tmp3 = g1.x*a0.w + g1.y*a1.w + g1.z*a2.w + g1.w*a3.w;

        // phase 2: out[e] = sum_s temp[s] * c3[s][k][e], e = 0..7
        const float* p3 = G3 + ko;
        const float4 b0l = *reinterpret_cast<const float4*>(p3);
        const float4 b0h = *reinterpret_cast<const float4*>(p3 + 4);
        const float4 b1l = *reinterpret_cast<const float4*>(p3 +     V3*D3);
        const float4 b1h = *reinterpret_cast<const float4*>(p3 +     V3*D3 + 4);
        const float4 b2l = *reinterpret_cast<const float4*>(p3 + 2 * V3*D3);
        const float4 b2h = *reinterpret_cast<const float4*>(p3 + 2 * V3*D3 + 4);
        const float4 b3l = *reinterpret_cast<const float4*>(p3 + 3 * V3*D3);
        const float4 b3h = *reinterpret_cast<const float4*>(p3 + 3 * V3*D3 + 4);

        float4 olo, ohi;
        olo.x = tmp0*b0l.x + tmp1*b1l.x + tmp2*b2l.x + tmp3*b3l.x;
        olo.y = tmp0*b0l.y + tmp1*b1l.y + tmp2*b2l.y + tmp3*b3l.y;
        olo.z = tmp0*b0l.z + tmp1*b1l.z + tmp2*b2l.z + tmp3*b3l.z;
        olo.w = tmp0*b0l.w + tmp1*b1l.w + tmp2*b2l.w + tmp3*b3l.w;
        ohi.x = tmp0*b0h.x + tmp1*b1h.x + tmp2*b2h.x + tmp3*b3h.x;
        ohi.y = tmp0*b0h.y + tmp1*b1h.y + tmp2*b2h.y + tmp3*b3h.y;
        ohi.z = tmp0*b0h.z + tmp1*b1h.z + tmp2*b2h.z + tmp3*b3h.z;
        ohi.w = tmp0*b0h.w + tmp1*b1h.w + tmp2*b2h.w + tmp3*b3h.w;

        if (tt + p < N) {
            *reinterpret_cast<float4*>(outp)     = olo;
            *reinterpret_cast<float4*>(outp + 4) = ohi;
        }
        outp += 512;   // 2 tokens
    }
}

extern "C" void kernel_launch(void* const* d_in, const int* in_sizes, int n_in,
                              void* d_out, int out_size, void* d_ws, size_t ws_size,
                              hipStream_t stream) {
    const int*   ids = (const int*)d_in[0];
    const float* cr1 = (const float*)d_in[1];
    const float* cr2 = (const float*)d_in[2];
    const float* cr3 = (const float*)d_in[3];
    const float* ci1 = (const float*)d_in[4];
    const float* ci2 = (const float*)d_in[5];
    const float* ci3 = (const float*)d_in[6];
    float* out = (float*)d_out;

    const int N = in_sizes[0];
    const int tokens_per_block = (BLOCK / 64) * TPW;                   // 128
    const int blocks = (N + tokens_per_block - 1) / tokens_per_block;  // 1024 @ N=131072

    tt_embed_kernel<<<blocks, BLOCK, 0, stream>>>(ids, cr1, cr2, cr3, ci1, ci2, ci3, out, N);
}